// Round 12
// baseline (400.237 us; speedup 1.0000x reference)
//
#include <hip/hip_runtime.h>
#include <hip/hip_bf16.h>
#include <math.h>

#define Bb   64
#define Nn   256
#define Mm   16
#define ONF  92
#define OEF  41
#define NF   128
#define EF   64
#define KDIM 320   // 2*NF + EF
#define ODIM 256   // 2*NF
#define FINAL 128
#define K0C  6     // conv K-chunks (K=192: gather 128 + edge 64)

typedef __attribute__((ext_vector_type(8))) short short8;
typedef __attribute__((ext_vector_type(4))) float f32x4;

__device__ __forceinline__ float sigmoidf_(float x) {
    float e = __expf(-x);
    return __builtin_amdgcn_rcpf(1.0f + e);
}
__device__ __forceinline__ float softplusf_(float x) {
    return fmaxf(x, 0.0f) + __logf(1.0f + __expf(-fabsf(x)));
}
__device__ __forceinline__ __hip_bfloat16 to_bf16(float x) { return __float2bfloat16(x); }

// ---------- mega-prep: all weight swizzles + WeT + DA in ONE launch ----------
__device__ __forceinline__ void swz(const float* __restrict__ in, __hip_bfloat16* __restrict__ out,
                                    int t, int Itot, int koff, int Kuse, int K0)
{
    int j = t & 7;
    int u = t >> 3;
    int lane = u & 63;
    int ln16 = lane & 15, q = lane >> 4;
    int v = u >> 6;
    int k0 = v % K0, tile = v / K0;
    int n = tile * 16 + ln16, k = k0 * 32 + q * 8 + j;
    out[t] = (k < Kuse) ? to_bf16(in[(size_t)n * Itot + koff + k]) : to_bf16(0.0f);
}

#define SZ_WET (OEF * EF)          // 2624
#define SZ_WB  (16 * K0C * 512)    // 49152
#define SZ_WS  (16 * 4 * 512)      // 32768
#define SZ_WNB ((NF / 16) * 3 * 512)
#define SZ_WEB ((EF / 16) * 2 * 512)
#define SZ_WFB ((64 / 16) * 4 * 512)
#define SZ_DA  (Nn * Nn)
#define PREP_TOTAL (SZ_WET + 3 * SZ_WB + 3 * SZ_WS + SZ_WNB + SZ_WEB + SZ_WFB + SZ_DA)

__global__ __launch_bounds__(256) void k_prep(
    const float* __restrict__ We, const float* __restrict__ W1,
    const float* __restrict__ W2, const float* __restrict__ W3,
    const float* __restrict__ Wn, const float* __restrict__ Wf,
    const float* __restrict__ dis, const float* __restrict__ pw, const float* __restrict__ pb,
    float* __restrict__ WeT,
    __hip_bfloat16* __restrict__ W1b, __hip_bfloat16* __restrict__ W2b, __hip_bfloat16* __restrict__ W3b,
    __hip_bfloat16* __restrict__ W1s, __hip_bfloat16* __restrict__ W2s, __hip_bfloat16* __restrict__ W3s,
    __hip_bfloat16* __restrict__ Wnb, __hip_bfloat16* __restrict__ Web, __hip_bfloat16* __restrict__ Wfb,
    __hip_bfloat16* __restrict__ DAf)
{
    int t = blockIdx.x * 256 + threadIdx.x;
    if (t < SZ_WET) {
        int o = t / OEF, i = t - o * OEF;
        WeT[i * EF + o] = We[t];
        return;
    }
    t -= SZ_WET;
    if (t < SZ_WB) { swz(W1, W1b, t, KDIM, NF, 192, K0C); return; }
    t -= SZ_WB;
    if (t < SZ_WB) { swz(W2, W2b, t, KDIM, NF, 192, K0C); return; }
    t -= SZ_WB;
    if (t < SZ_WB) { swz(W3, W3b, t, KDIM, NF, 192, K0C); return; }
    t -= SZ_WB;
    if (t < SZ_WS) { swz(W1, W1s, t, KDIM, 0, NF, 4); return; }
    t -= SZ_WS;
    if (t < SZ_WS) { swz(W2, W2s, t, KDIM, 0, NF, 4); return; }
    t -= SZ_WS;
    if (t < SZ_WS) { swz(W3, W3s, t, KDIM, 0, NF, 4); return; }
    t -= SZ_WS;
    if (t < SZ_WNB) { swz(Wn, Wnb, t, ONF, 0, ONF, 3); return; }
    t -= SZ_WNB;
    if (t < SZ_WEB) { swz(We, Web, t, OEF, 0, OEF, 2); return; }
    t -= SZ_WEB;
    if (t < SZ_WFB) { swz(Wf, Wfb, t, NF, 0, NF, 4); return; }
    t -= SZ_WFB;
    if (t < SZ_DA) {
        int i = t >> 8, jx = t & 255;
        float v = sigmoidf_(fmaf(*pw, dis[t], *pb));
        int itile = i >> 4, ln16 = i & 15;
        int k0 = jx >> 5, q = (jx >> 3) & 3, jj = jx & 7;
        DAf[(size_t)((((itile * 8 + k0) << 6) + (q << 4) + ln16)) * 8 + jj] = to_bf16(v);
    }
}

// ---------- generic MFMA embed body ----------
template<int KIN, int K0, int NCOLS>
__device__ __forceinline__ void emb_body(
    int bid, const float* __restrict__ X, const __hip_bfloat16* __restrict__ Bswz,
    const float* __restrict__ bias, __hip_bfloat16* __restrict__ Y,
    __hip_bfloat16* A_s, __hip_bfloat16* O_s)
{
    constexpr int KP = K0 * 32;
    constexpr int TPW = NCOLS / 64;
    constexpr int OLD = NCOLS + 24;

    const int row0 = bid * 64;
    const int t = threadIdx.x;

    {
        const float4* Xb = (const float4*)(X + (size_t)row0 * KIN);
        constexpr int NV = (64 * KIN) / 4;
        for (int c = t; c < NV; c += 256) {
            float4 v = Xb[c];
            int flat = c * 4;
            #pragma unroll
            for (int e = 0; e < 4; e++) {
                int f = flat + e;
                int row = f / KIN, k = f - row * KIN;
                int mt = row >> 4, ln16 = row & 15;
                int k0 = k >> 5, q = (k >> 3) & 3, j = k & 7;
                float vv = (e == 0) ? v.x : (e == 1) ? v.y : (e == 2) ? v.z : v.w;
                A_s[(((mt * K0 + k0) << 6) + (q << 4) + ln16) * 8 + j] = to_bf16(vv);
            }
        }
        constexpr int PAD = KP - KIN;
        for (int c = t; c < 64 * PAD; c += 256) {
            int row = c / PAD, k = KIN + (c - row * PAD);
            int mt = row >> 4, ln16 = row & 15;
            int k0 = k >> 5, q = (k >> 3) & 3, j = k & 7;
            A_s[(((mt * K0 + k0) << 6) + (q << 4) + ln16) * 8 + j] = to_bf16(0.0f);
        }
    }
    __syncthreads();

    const int wv = t >> 6, lane = t & 63;
    const int q = lane >> 4, ln16 = lane & 15;

    f32x4 acc[4][TPW];
    #pragma unroll
    for (int p = 0; p < TPW; p++) {
        float bv = bias[(wv * TPW + p) * 16 + ln16];
        #pragma unroll
        for (int mt = 0; mt < 4; mt++) acc[mt][p] = (f32x4){bv, bv, bv, bv};
    }

    short8 bw[TPW][K0];
    #pragma unroll
    for (int p = 0; p < TPW; p++)
        #pragma unroll
        for (int k0 = 0; k0 < K0; k0++)
            bw[p][k0] = *(const short8*)(Bswz + ((size_t)((wv * TPW + p) * K0 + k0) << 9) + (lane << 3));

    #pragma unroll
    for (int k0 = 0; k0 < K0; k0++) {
        short8 af[4];
        #pragma unroll
        for (int mt = 0; mt < 4; mt++)
            af[mt] = *(const short8*)(A_s + (((mt * K0 + k0) << 6) + lane) * 8);
        #pragma unroll
        for (int mt = 0; mt < 4; mt++)
            #pragma unroll
            for (int p = 0; p < TPW; p++)
                acc[mt][p] = __builtin_amdgcn_mfma_f32_16x16x32_bf16(af[mt], bw[p][k0], acc[mt][p], 0, 0, 0);
    }

    #pragma unroll
    for (int mt = 0; mt < 4; mt++)
        #pragma unroll
        for (int p = 0; p < TPW; p++) {
            int col = (wv * TPW + p) * 16 + ln16;
            #pragma unroll
            for (int r = 0; r < 4; r++)
                O_s[(mt * 16 + q * 4 + r) * OLD + col] = to_bf16(acc[mt][p][r]);
        }
    __syncthreads();
    constexpr int CH = NCOLS / 8;
    for (int c = t; c < 64 * CH; c += 256) {
        int row = c / CH, ch = c - row * CH;
        *(uint4*)(Y + (size_t)(row0 + row) * NCOLS + ch * 8) =
            *(const uint4*)(O_s + row * OLD + ch * 8);
    }
}

// blocks [0,256): node embed; [256, 256+4096): edge embed
__global__ __launch_bounds__(256) void k_embed_all(
    const float* __restrict__ node_fea, const __hip_bfloat16* __restrict__ Wnb,
    const float* __restrict__ bn, __hip_bfloat16* __restrict__ nf0,
    const float* __restrict__ edge_fea, const __hip_bfloat16* __restrict__ Web,
    const float* __restrict__ be, __hip_bfloat16* __restrict__ efb)
{
    __shared__ __align__(16) __hip_bfloat16 A_s[4 * 3 * 512];
    __shared__ __align__(16) __hip_bfloat16 O_s[64 * (NF + 24)];
    if (blockIdx.x < 256)
        emb_body<ONF, 3, NF>(blockIdx.x, node_fea, Wnb, bn, nf0, A_s, O_s);
    else
        emb_body<OEF, 2, EF>(blockIdx.x - 256, edge_fea, Web, be, efb, A_s, O_s);
}

// ---------- conv layer: 512 thr / 8 waves, 4 node-groups per block,
// single LDS buffer, register-prefetch pipeline with ROLE-OVERLAID regs ----------
template<bool PRECOMP>
__global__ __launch_bounds__(512, 4) void k_conv_mfma(
    const __hip_bfloat16* __restrict__ nf_in,   // [B*N][NF] bf16
    const float* __restrict__ edge_fea,         // [B*N*M][OEF] f32  (PRECOMP=false)
    const __hip_bfloat16* __restrict__ ef_bf,   // [B*N*M][EF] bf16  (PRECOMP=true)
    const int*   __restrict__ eidx,             // [B*N][M]
    const float* __restrict__ WeT,              // [OEF][EF] f32     (PRECOMP=false)
    const float* __restrict__ be,               // [EF]              (PRECOMP=false)
    const __hip_bfloat16* __restrict__ Wb,      // [16][K0C][64][8] (W[:,128:320])
    const __hip_bfloat16* __restrict__ Wsb,     // [16][4][64][8]   (W[:,0:128])
    const float* __restrict__ bias,             // [ODIM]
    const float* __restrict__ palpha,
    __hip_bfloat16* __restrict__ nf_out)        // [B*N][NF] bf16
{
    __shared__ __align__(16) __hip_bfloat16 A_s[4 * K0C * 512];   // 24576 B
    __shared__ __align__(16) __hip_bfloat16 A_sf[4 * 512];        //  4096 B

    const int node00 = blockIdx.x * 16;
    const int b = node00 >> 8;
    const int t = threadIdx.x;
    const int wv = t >> 6, lane = t & 63;
    const int q = lane >> 4, ln16 = lane & 15;
    const int v4 = wv & 3;                      // node index within group for this wave
    const float alpha = *palpha;

    // prefetch eidx-derived state for all 4 groups (static indexing via unroll)
    int ej[4];
    unsigned long long mb[4];
    #pragma unroll
    for (int g = 0; g < 4; g++) {
        int node0 = node00 + g * 4;
        mb[g] = __ballot(eidx[node0 * Mm + lane] >= 0);
        int j = eidx[(node0 + v4) * Mm + ln16];
        ej[g] = j < 0 ? 0 : j;
    }

    // ROLE-OVERLAID prefetch registers: waves<4 use R[0..3] (gather rows);
    // waves>=4 use R[0]=E0, R[1]=E1, R[2]=S. Peak liveness 16 VGPRs, not 28.
    uint4 R[4];

    auto load_regs = [&](int g) {
        const int node0 = node00 + g * 4;
        if (wv < 4) {
            const __hip_bfloat16* gp = nf_in + (size_t)((b << 8) + ej[g]) * NF + q * 8;
            R[0] = *(const uint4*)(gp);
            R[1] = *(const uint4*)(gp + 32);
            R[2] = *(const uint4*)(gp + 64);
            R[3] = *(const uint4*)(gp + 96);
        } else {
            if (PRECOMP) {
                const __hip_bfloat16* ep =
                    ef_bf + ((size_t)(node0 * Mm) + v4 * 16 + ln16) * EF + q * 8;
                R[0] = *(const uint4*)(ep);
                R[1] = *(const uint4*)(ep + 32);
            }
            R[2] = *(const uint4*)(nf_in + (size_t)(node0 + (ln16 & 3)) * NF + v4 * 32 + q * 8);
        }
    };

    // regs -> LDS, fragment order, conflict-free (base + lane*16)
    auto write_lds = [&](int g) {
        if (wv < 4) {
            *(uint4*)(A_s + ((wv * K0C + 0) * 64 + lane) * 8) = R[0];
            *(uint4*)(A_s + ((wv * K0C + 1) * 64 + lane) * 8) = R[1];
            *(uint4*)(A_s + ((wv * K0C + 2) * 64 + lane) * 8) = R[2];
            *(uint4*)(A_s + ((wv * K0C + 3) * 64 + lane) * 8) = R[3];
        } else {
            if (PRECOMP) {
                *(uint4*)(A_s + ((v4 * K0C + 4) * 64 + lane) * 8) = R[0];
                *(uint4*)(A_s + ((v4 * K0C + 5) * 64 + lane) * 8) = R[1];
            }
            *(uint4*)(A_sf + (v4 * 64 + lane) * 8) = R[2];
        }
        if (!PRECOMP) {
            const int node0 = node00 + g * 4;
            for (int c = t; c < 64 * EF; c += 512) {
                int rr = c >> 6, col = c & 63;
                float a = be[col];
                const float* er = edge_fea + (size_t)(node0 * Mm + rr) * OEF;
                #pragma unroll
                for (int i = 0; i < OEF; i++) a = fmaf(er[i], WeT[i * EF + col], a);
                int mt = rr >> 4, l16 = rr & 15;
                int k0 = 4 + (col >> 5), qq = (col >> 3) & 3, jj = col & 7;
                A_s[((mt * K0C + k0) * 64 + qq * 16 + l16) * 8 + jj] = to_bf16(a);
            }
        }
    };

    // compute group g
    auto compute = [&](int g) {
        const int node0 = node00 + g * 4;

        // self-term S via MFMA: wave w -> tiles w (F) and w+8 (C)
        f32x4 sv0, sv1;
        {
            float bF = bias[wv * 16 + ln16], bC = bias[(wv + 8) * 16 + ln16];
            sv0 = (f32x4){bF, bF, bF, bF};
            sv1 = (f32x4){bC, bC, bC, bC};
        }
        #pragma unroll
        for (int k0 = 0; k0 < 4; k0++) {
            short8 afs = *(const short8*)(A_sf + (k0 * 64 + lane) * 8);
            short8 bws0 = *(const short8*)(Wsb + ((size_t)(wv * 4 + k0) << 9) + (lane << 3));
            short8 bws1 = *(const short8*)(Wsb + ((size_t)((wv + 8) * 4 + k0) << 9) + (lane << 3));
            sv0 = __builtin_amdgcn_mfma_f32_16x16x32_bf16(afs, bws0, sv0, 0, 0, 0);
            sv1 = __builtin_amdgcn_mfma_f32_16x16x32_bf16(afs, bws1, sv1, 0, 0, 0);
        }

        f32x4 accF[4], accC[4];
        #pragma unroll
        for (int mt = 0; mt < 4; mt++) {
            float vF = __shfl(sv0[mt], ln16);
            float vC = __shfl(sv1[mt], ln16);
            accF[mt] = (f32x4){vF, vF, vF, vF};
            accC[mt] = (f32x4){vC, vC, vC, vC};
        }

        const __hip_bfloat16* WF = Wb + (size_t)wv * (K0C * 512) + (lane << 3);
        const __hip_bfloat16* WC = Wb + (size_t)(wv + 8) * (K0C * 512) + (lane << 3);
        #pragma unroll
        for (int k0 = 0; k0 < K0C; k0++) {
            short8 bwF = *(const short8*)(WF + k0 * 512);
            short8 bwC = *(const short8*)(WC + k0 * 512);
            short8 af[4];
            #pragma unroll
            for (int mt = 0; mt < 4; mt++)
                af[mt] = *(const short8*)(A_s + ((mt * K0C + k0) * 64 + lane) * 8);
            #pragma unroll
            for (int mt = 0; mt < 4; mt++) {
                accF[mt] = __builtin_amdgcn_mfma_f32_16x16x32_bf16(af[mt], bwF, accF[mt], 0, 0, 0);
                accC[mt] = __builtin_amdgcn_mfma_f32_16x16x32_bf16(af[mt], bwC, accC[mt], 0, 0, 0);
            }
        }

        #pragma unroll
        for (int mt = 0; mt < 4; mt++) {
            const int gnode = node0 + mt;
            unsigned mbits = (unsigned)(mb[g] >> (mt * 16 + q * 4)) & 0xFu;
            float partial = 0.0f;
            #pragma unroll
            for (int r = 0; r < 4; r++) {
                bool msk = (mbits >> r) & 1u;
                float f = sigmoidf_(accF[mt][r]);
                float c = softplusf_(accC[mt][r]);
                partial += msk ? f * c : 0.0f;
            }
            partial += __shfl_xor(partial, 16);
            partial += __shfl_xor(partial, 32);
            if (q == 0) {
                int col = wv * 16 + ln16;
                float self = __bfloat162float(nf_in[(size_t)gnode * NF + col]);
                nf_out[(size_t)gnode * NF + col] = to_bf16(softplusf_(fmaf(alpha, self, partial)));
            }
        }
    };

    load_regs(0);
    #pragma unroll
    for (int g = 0; g < 4; g++) {
        if (g > 0) __syncthreads();   // previous compute done reading LDS
        write_lds(g);
        __syncthreads();              // buffer fully staged
        if (g < 3) load_regs(g + 1);  // prefetch next group; waited at next write_lds
        compute(g);
    }
}

// ---------- final linear (MFMA): out[:, :, 0:64] = nf3 @ Wf^T + bf ----------
__global__ __launch_bounds__(256) void k_final_mfma(
    const __hip_bfloat16* __restrict__ nf, const __hip_bfloat16* __restrict__ Wfb,
    const float* __restrict__ bfv, float* __restrict__ out,
    __hip_bfloat16* __restrict__ XT)
{
    __shared__ __align__(16) __hip_bfloat16 A_s[16 * 512];
    const int node0 = blockIdx.x * 64;
    const int bloc = node0 >> 8;
    const int t = threadIdx.x;
    const int wv = t >> 6, lane = t & 63;
    const int q = lane >> 4, ln16 = lane & 15;

    const __hip_bfloat16* rowp = nf + (size_t)(node0 + (wv << 4) + ln16) * NF;
    #pragma unroll
    for (int k0 = 0; k0 < 4; k0++)
        *(uint4*)(A_s + ((wv * 4 + k0) * 64 + lane) * 8) =
            *(const uint4*)(rowp + k0 * 32 + q * 8);
    __syncthreads();

    short8 bw[4];
    #pragma unroll
    for (int k0 = 0; k0 < 4; k0++)
        bw[k0] = *(const short8*)(Wfb + ((size_t)(wv * 4 + k0) * 64 + lane) * 8);

    float bv = bfv[wv * 16 + ln16];
    f32x4 acc[4];
    #pragma unroll
    for (int mt = 0; mt < 4; mt++) acc[mt] = (f32x4){bv, bv, bv, bv};

    #pragma unroll
    for (int k0 = 0; k0 < 4; k0++) {
        short8 af[4];
        #pragma unroll
        for (int mt = 0; mt < 4; mt++)
            af[mt] = *(const short8*)(A_s + ((mt * 4 + k0) * 64 + lane) * 8);
        #pragma unroll
        for (int mt = 0; mt < 4; mt++)
            acc[mt] = __builtin_amdgcn_mfma_f32_16x16x32_bf16(af[mt], bw[k0], acc[mt], 0, 0, 0);
    }

    const int col = (wv << 4) + ln16;
    #pragma unroll
    for (int mt = 0; mt < 4; mt++)
        #pragma unroll
        for (int r = 0; r < 4; r++) {
            int row = mt * 16 + q * 4 + r;
            float v = acc[mt][r];
            out[(size_t)(node0 + row) * FINAL + col] = v;
            XT[(size_t)(bloc * 64 + col) * 256 + (node0 & 255) + row] = to_bf16(v);
        }
}

// ---------- node1 (MFMA): out[:, :, 64:128] = DA @ nff per batch ----------
__global__ __launch_bounds__(256) void k_node1_mfma(
    const __hip_bfloat16* __restrict__ DAf,   // A-fragment order [16][8][64][8]
    const __hip_bfloat16* __restrict__ XT,    // [B][64 f][256 j] bf16
    float* __restrict__ out)
{
    __shared__ __align__(16) __hip_bfloat16 B_s[32 * 512];
    const int blk = blockIdx.x;
    const int b = blk >> 2, i0 = (blk & 3) * 64;
    const int t = threadIdx.x;
    const int wv = t >> 6, lane = t & 63;
    const int q = lane >> 4, ln16 = lane & 15;

    const __hip_bfloat16* xrow = XT + (size_t)(b * 64 + (wv << 4) + ln16) * 256;
    #pragma unroll
    for (int k0 = 0; k0 < 8; k0++)
        *(uint4*)(B_s + ((wv * 8 + k0) * 64 + lane) * 8) =
            *(const uint4*)(xrow + k0 * 32 + q * 8);
    __syncthreads();

    f32x4 acc[4];
    #pragma unroll
    for (int mt = 0; mt < 4; mt++) acc[mt] = (f32x4){0.f, 0.f, 0.f, 0.f};

    #pragma unroll
    for (int k0 = 0; k0 < 8; k0++) {
        short8 bfr = *(const short8*)(B_s + ((wv * 8 + k0) * 64 + lane) * 8);
        short8 af[4];
        #pragma unroll
        for (int mt = 0; mt < 4; mt++)
            af[mt] = *(const short8*)(DAf + (size_t)(((i0 >> 4) + mt) * 8 + k0) * 512 + (lane << 3));
        #pragma unroll
        for (int mt = 0; mt < 4; mt++)
            acc[mt] = __builtin_amdgcn_mfma_f32_16x16x32_bf16(af[mt], bfr, acc[mt], 0, 0, 0);
    }

    #pragma unroll
    for (int mt = 0; mt < 4; mt++)
        #pragma unroll
        for (int r = 0; r < 4; r++) {
            int i = i0 + mt * 16 + q * 4 + r;
            out[(size_t)((b << 8) + i) * FINAL + 64 + (wv << 4) + ln16] = acc[mt][r];
        }
}

extern "C" void kernel_launch(void* const* d_in, const int* in_sizes, int n_in,
                              void* d_out, int out_size, void* d_ws, size_t ws_size,
                              hipStream_t stream)
{
    const float* node_fea = (const float*)d_in[0];
    const float* edge_fea = (const float*)d_in[1];
    const int*   eidx     = (const int*)  d_in[2];
    const float* dis      = (const float*)d_in[3];
    const float* Wn = (const float*)d_in[4];
    const float* bn = (const float*)d_in[5];
    const float* We = (const float*)d_in[6];
    const float* be = (const float*)d_in[7];
    const float* W1 = (const float*)d_in[8];
    const float* b1 = (const float*)d_in[9];
    const float* a1 = (const float*)d_in[10];
    const float* W2 = (const float*)d_in[11];
    const float* b2 = (const float*)d_in[12];
    const float* a2 = (const float*)d_in[13];
    const float* W3 = (const float*)d_in[14];
    const float* b3 = (const float*)d_in[15];
    const float* a3 = (const float*)d_in[16];
    const float* Wf = (const float*)d_in[17];
    const float* bf = (const float*)d_in[18];
    const float* DAw = (const float*)d_in[19];
    const float* DAb = (const float*)d_in[20];
    float* out = (float*)d_out;

    // workspace layout (bytes, 256-aligned blocks)
    char* base = (char*)d_ws;
    size_t off = 0;
    auto alloc = [&](size_t bytes) { char* p = base + off; off = (off + bytes + 255) & ~(size_t)255; return p; };
    __hip_bfloat16* nfA = (__hip_bfloat16*)alloc((size_t)Bb * Nn * NF * 2);
    __hip_bfloat16* nfB = (__hip_bfloat16*)alloc((size_t)Bb * Nn * NF * 2);
    __hip_bfloat16* W1b = (__hip_bfloat16*)alloc((size_t)SZ_WB * 2);
    __hip_bfloat16* W2b = (__hip_bfloat16*)alloc((size_t)SZ_WB * 2);
    __hip_bfloat16* W3b = (__hip_bfloat16*)alloc((size_t)SZ_WB * 2);
    __hip_bfloat16* W1s = (__hip_bfloat16*)alloc((size_t)SZ_WS * 2);
    __hip_bfloat16* W2s = (__hip_bfloat16*)alloc((size_t)SZ_WS * 2);
    __hip_bfloat16* W3s = (__hip_bfloat16*)alloc((size_t)SZ_WS * 2);
    float* WeT = (float*)alloc((size_t)OEF * EF * 4);
    __hip_bfloat16* DAf = (__hip_bfloat16*)alloc((size_t)Nn * Nn * 2);
    __hip_bfloat16* Wnb = (__hip_bfloat16*)alloc((size_t)SZ_WNB * 2);
    __hip_bfloat16* Web = (__hip_bfloat16*)alloc((size_t)SZ_WEB * 2);
    __hip_bfloat16* Wfb = (__hip_bfloat16*)alloc((size_t)SZ_WFB * 2);
    __hip_bfloat16* XT  = (__hip_bfloat16*)alloc((size_t)Bb * 64 * Nn * 2);
    __hip_bfloat16* efb = (__hip_bfloat16*)alloc((size_t)Bb * Nn * Mm * EF * 2);    // 33.5 MB
    const bool precomp = (ws_size >= off);

    hipLaunchKernelGGL(k_prep, dim3((PREP_TOTAL + 255) / 256), dim3(256), 0, stream,
                       We, W1, W2, W3, Wn, Wf, dis, DAw, DAb,
                       WeT, W1b, W2b, W3b, W1s, W2s, W3s, Wnb, Web, Wfb, DAf);

    hipLaunchKernelGGL(k_embed_all, dim3(precomp ? (256 + Bb * Nn * Mm / 64) : 256), dim3(256), 0, stream,
                       node_fea, Wnb, bn, nfA, edge_fea, Web, be, efb);

    const int NBC = Bb * Nn / 16;   // 1024 blocks, 4 groups each
    if (precomp) {
        hipLaunchKernelGGL((k_conv_mfma<true>), dim3(NBC), dim3(512), 0, stream,
                           nfA, edge_fea, efb, eidx, WeT, be, W1b, W1s, b1, a1, nfB);
        hipLaunchKernelGGL((k_conv_mfma<true>), dim3(NBC), dim3(512), 0, stream,
                           nfB, edge_fea, efb, eidx, WeT, be, W2b, W2s, b2, a2, nfA);
        hipLaunchKernelGGL((k_conv_mfma<true>), dim3(NBC), dim3(512), 0, stream,
                           nfA, edge_fea, efb, eidx, WeT, be, W3b, W3s, b3, a3, nfB);
    } else {
        hipLaunchKernelGGL((k_conv_mfma<false>), dim3(NBC), dim3(512), 0, stream,
                           nfA, edge_fea, efb, eidx, WeT, be, W1b, W1s, b1, a1, nfB);
        hipLaunchKernelGGL((k_conv_mfma<false>), dim3(NBC), dim3(512), 0, stream,
                           nfB, edge_fea, efb, eidx, WeT, be, W2b, W2s, b2, a2, nfA);
        hipLaunchKernelGGL((k_conv_mfma<false>), dim3(NBC), dim3(512), 0, stream,
                           nfA, edge_fea, efb, eidx, WeT, be, W3b, W3s, b3, a3, nfB);
    }

    hipLaunchKernelGGL(k_final_mfma, dim3(Bb * Nn / 64), dim3(256), 0, stream, nfB, Wfb, bf, out, XT);
    hipLaunchKernelGGL(k_node1_mfma, dim3(Bb * 4), dim3(256), 0, stream, DAf, XT, out);
}

// Round 13
// 304.083 us; speedup vs baseline: 1.3162x; 1.3162x over previous
//
#include <hip/hip_runtime.h>
#include <hip/hip_bf16.h>
#include <math.h>

#define Bb   64
#define Nn   256
#define Mm   16
#define ONF  92
#define OEF  41
#define NF   128
#define EF   64
#define KDIM 320   // 2*NF + EF
#define ODIM 256   // 2*NF
#define FINAL 128
#define K0C  6     // conv K-chunks (K=192: gather 128 + edge 64)

typedef __attribute__((ext_vector_type(8))) short short8;
typedef __attribute__((ext_vector_type(4))) float f32x4;

__device__ __forceinline__ float sigmoidf_(float x) {
    float e = __expf(-x);
    return __builtin_amdgcn_rcpf(1.0f + e);
}
__device__ __forceinline__ float softplusf_(float x) {
    return fmaxf(x, 0.0f) + __logf(1.0f + __expf(-fabsf(x)));
}
__device__ __forceinline__ __hip_bfloat16 to_bf16(float x) { return __float2bfloat16(x); }

// ---------- mega-prep: all weight swizzles + WeT + DA in ONE launch ----------
__device__ __forceinline__ void swz(const float* __restrict__ in, __hip_bfloat16* __restrict__ out,
                                    int t, int Itot, int koff, int Kuse, int K0)
{
    int j = t & 7;
    int u = t >> 3;
    int lane = u & 63;
    int ln16 = lane & 15, q = lane >> 4;
    int v = u >> 6;
    int k0 = v % K0, tile = v / K0;
    int n = tile * 16 + ln16, k = k0 * 32 + q * 8 + j;
    out[t] = (k < Kuse) ? to_bf16(in[(size_t)n * Itot + koff + k]) : to_bf16(0.0f);
}

#define SZ_WET (OEF * EF)          // 2624
#define SZ_WB  (16 * K0C * 512)    // 49152
#define SZ_WS  (16 * 4 * 512)      // 32768
#define SZ_WNB ((NF / 16) * 3 * 512)
#define SZ_WEB ((EF / 16) * 2 * 512)
#define SZ_WFB ((64 / 16) * 4 * 512)
#define SZ_DA  (Nn * Nn)
#define PREP_TOTAL (SZ_WET + 3 * SZ_WB + 3 * SZ_WS + SZ_WNB + SZ_WEB + SZ_WFB + SZ_DA)

__global__ __launch_bounds__(256) void k_prep(
    const float* __restrict__ We, const float* __restrict__ W1,
    const float* __restrict__ W2, const float* __restrict__ W3,
    const float* __restrict__ Wn, const float* __restrict__ Wf,
    const float* __restrict__ dis, const float* __restrict__ pw, const float* __restrict__ pb,
    float* __restrict__ WeT,
    __hip_bfloat16* __restrict__ W1b, __hip_bfloat16* __restrict__ W2b, __hip_bfloat16* __restrict__ W3b,
    __hip_bfloat16* __restrict__ W1s, __hip_bfloat16* __restrict__ W2s, __hip_bfloat16* __restrict__ W3s,
    __hip_bfloat16* __restrict__ Wnb, __hip_bfloat16* __restrict__ Web, __hip_bfloat16* __restrict__ Wfb,
    __hip_bfloat16* __restrict__ DAf)
{
    int t = blockIdx.x * 256 + threadIdx.x;
    if (t < SZ_WET) {
        int o = t / OEF, i = t - o * OEF;
        WeT[i * EF + o] = We[t];
        return;
    }
    t -= SZ_WET;
    if (t < SZ_WB) { swz(W1, W1b, t, KDIM, NF, 192, K0C); return; }
    t -= SZ_WB;
    if (t < SZ_WB) { swz(W2, W2b, t, KDIM, NF, 192, K0C); return; }
    t -= SZ_WB;
    if (t < SZ_WB) { swz(W3, W3b, t, KDIM, NF, 192, K0C); return; }
    t -= SZ_WB;
    if (t < SZ_WS) { swz(W1, W1s, t, KDIM, 0, NF, 4); return; }
    t -= SZ_WS;
    if (t < SZ_WS) { swz(W2, W2s, t, KDIM, 0, NF, 4); return; }
    t -= SZ_WS;
    if (t < SZ_WS) { swz(W3, W3s, t, KDIM, 0, NF, 4); return; }
    t -= SZ_WS;
    if (t < SZ_WNB) { swz(Wn, Wnb, t, ONF, 0, ONF, 3); return; }
    t -= SZ_WNB;
    if (t < SZ_WEB) { swz(We, Web, t, OEF, 0, OEF, 2); return; }
    t -= SZ_WEB;
    if (t < SZ_WFB) { swz(Wf, Wfb, t, NF, 0, NF, 4); return; }
    t -= SZ_WFB;
    if (t < SZ_DA) {
        int i = t >> 8, jx = t & 255;
        float v = sigmoidf_(fmaf(*pw, dis[t], *pb));
        int itile = i >> 4, ln16 = i & 15;
        int k0 = jx >> 5, q = (jx >> 3) & 3, jj = jx & 7;
        DAf[(size_t)((((itile * 8 + k0) << 6) + (q << 4) + ln16)) * 8 + jj] = to_bf16(v);
    }
}

// ---------- generic MFMA embed body ----------
template<int KIN, int K0, int NCOLS>
__device__ __forceinline__ void emb_body(
    int bid, const float* __restrict__ X, const __hip_bfloat16* __restrict__ Bswz,
    const float* __restrict__ bias, __hip_bfloat16* __restrict__ Y,
    __hip_bfloat16* A_s, __hip_bfloat16* O_s)
{
    constexpr int KP = K0 * 32;
    constexpr int TPW = NCOLS / 64;
    constexpr int OLD = NCOLS + 24;

    const int row0 = bid * 64;
    const int t = threadIdx.x;

    {
        const float4* Xb = (const float4*)(X + (size_t)row0 * KIN);
        constexpr int NV = (64 * KIN) / 4;
        for (int c = t; c < NV; c += 256) {
            float4 v = Xb[c];
            int flat = c * 4;
            #pragma unroll
            for (int e = 0; e < 4; e++) {
                int f = flat + e;
                int row = f / KIN, k = f - row * KIN;
                int mt = row >> 4, ln16 = row & 15;
                int k0 = k >> 5, q = (k >> 3) & 3, j = k & 7;
                float vv = (e == 0) ? v.x : (e == 1) ? v.y : (e == 2) ? v.z : v.w;
                A_s[(((mt * K0 + k0) << 6) + (q << 4) + ln16) * 8 + j] = to_bf16(vv);
            }
        }
        constexpr int PAD = KP - KIN;
        for (int c = t; c < 64 * PAD; c += 256) {
            int row = c / PAD, k = KIN + (c - row * PAD);
            int mt = row >> 4, ln16 = row & 15;
            int k0 = k >> 5, q = (k >> 3) & 3, j = k & 7;
            A_s[(((mt * K0 + k0) << 6) + (q << 4) + ln16) * 8 + j] = to_bf16(0.0f);
        }
    }
    __syncthreads();

    const int wv = t >> 6, lane = t & 63;
    const int q = lane >> 4, ln16 = lane & 15;

    f32x4 acc[4][TPW];
    #pragma unroll
    for (int p = 0; p < TPW; p++) {
        float bv = bias[(wv * TPW + p) * 16 + ln16];
        #pragma unroll
        for (int mt = 0; mt < 4; mt++) acc[mt][p] = (f32x4){bv, bv, bv, bv};
    }

    short8 bw[TPW][K0];
    #pragma unroll
    for (int p = 0; p < TPW; p++)
        #pragma unroll
        for (int k0 = 0; k0 < K0; k0++)
            bw[p][k0] = *(const short8*)(Bswz + ((size_t)((wv * TPW + p) * K0 + k0) << 9) + (lane << 3));

    #pragma unroll
    for (int k0 = 0; k0 < K0; k0++) {
        short8 af[4];
        #pragma unroll
        for (int mt = 0; mt < 4; mt++)
            af[mt] = *(const short8*)(A_s + (((mt * K0 + k0) << 6) + lane) * 8);
        #pragma unroll
        for (int mt = 0; mt < 4; mt++)
            #pragma unroll
            for (int p = 0; p < TPW; p++)
                acc[mt][p] = __builtin_amdgcn_mfma_f32_16x16x32_bf16(af[mt], bw[p][k0], acc[mt][p], 0, 0, 0);
    }

    #pragma unroll
    for (int mt = 0; mt < 4; mt++)
        #pragma unroll
        for (int p = 0; p < TPW; p++) {
            int col = (wv * TPW + p) * 16 + ln16;
            #pragma unroll
            for (int r = 0; r < 4; r++)
                O_s[(mt * 16 + q * 4 + r) * OLD + col] = to_bf16(acc[mt][p][r]);
        }
    __syncthreads();
    constexpr int CH = NCOLS / 8;
    for (int c = t; c < 64 * CH; c += 256) {
        int row = c / CH, ch = c - row * CH;
        *(uint4*)(Y + (size_t)(row0 + row) * NCOLS + ch * 8) =
            *(const uint4*)(O_s + row * OLD + ch * 8);
    }
}

// blocks [0,256): node embed; [256, 256+4096): edge embed
__global__ __launch_bounds__(256) void k_embed_all(
    const float* __restrict__ node_fea, const __hip_bfloat16* __restrict__ Wnb,
    const float* __restrict__ bn, __hip_bfloat16* __restrict__ nf0,
    const float* __restrict__ edge_fea, const __hip_bfloat16* __restrict__ Web,
    const float* __restrict__ be, __hip_bfloat16* __restrict__ efb)
{
    __shared__ __align__(16) __hip_bfloat16 A_s[4 * 3 * 512];
    __shared__ __align__(16) __hip_bfloat16 O_s[64 * (NF + 24)];
    if (blockIdx.x < 256)
        emb_body<ONF, 3, NF>(blockIdx.x, node_fea, Wnb, bn, nf0, A_s, O_s);
    else
        emb_body<OEF, 2, EF>(blockIdx.x - 256, edge_fea, Web, be, efb, A_s, O_s);
}

// ---------- conv layer: MFMA, K=192, self-term fused via in-kernel MFMA ----------
// (round-8 structure — best measured; A_sf staging made conflict-free)
template<bool PRECOMP>
__global__ __launch_bounds__(256, 3) void k_conv_mfma(
    const __hip_bfloat16* __restrict__ nf_in,   // [B*N][NF] bf16
    const float* __restrict__ edge_fea,         // [B*N*M][OEF] f32  (PRECOMP=false)
    const __hip_bfloat16* __restrict__ ef_bf,   // [B*N*M][EF] bf16  (PRECOMP=true)
    const int*   __restrict__ eidx,             // [B*N][M]
    const float* __restrict__ WeT,              // [OEF][EF] f32     (PRECOMP=false)
    const float* __restrict__ be,               // [EF]              (PRECOMP=false)
    const __hip_bfloat16* __restrict__ Wb,      // [16][K0C][64][8] (W[:,128:320])
    const __hip_bfloat16* __restrict__ Wsb,     // [16][4][64][8]   (W[:,0:128])
    const float* __restrict__ bias,             // [ODIM]
    const float* __restrict__ palpha,
    __hip_bfloat16* __restrict__ nf_out)        // [B*N][NF] bf16
{
    __shared__ __align__(16) __hip_bfloat16 A_s[4 * K0C * 512];   // 24576 B
    __shared__ __align__(16) __hip_bfloat16 A_sf[4 * 512];        //  4096 B (self rows 0..3)

    const int node0 = blockIdx.x * 4;
    const int b = node0 >> 8;
    const int t = threadIdx.x;
    const int wv = t >> 6, lane = t & 63;
    const int q = lane >> 4, ln16 = lane & 15;
    const int row = (wv << 4) + ln16;                 // this lane's A-tile row

    const int myidx = eidx[node0 * Mm + row];
    const unsigned long long mball = __ballot(eidx[node0 * Mm + lane] >= 0);

    // stage A (fragment order; conflict-free base + lane*16)
    {
        int j = myidx < 0 ? 0 : myidx;
        const __hip_bfloat16* gathp = nf_in + (size_t)((b << 8) + j) * NF;
        #pragma unroll
        for (int k0 = 0; k0 < 4; k0++)
            *(uint4*)(A_s + ((wv * K0C + k0) * 64 + lane) * 8) =
                *(const uint4*)(gathp + k0 * 32 + q * 8);
        // self rows, conflict-free: wave wv stages slot wv; rows m=4..15 become
        // copies of m&3 (harmless — self-MFMA rows 4..15 are discarded).
        *(uint4*)(A_sf + (wv * 64 + lane) * 8) =
            *(const uint4*)(nf_in + (size_t)(node0 + (ln16 & 3)) * NF + wv * 32 + q * 8);
        if (PRECOMP) {
            const __hip_bfloat16* efp = ef_bf + (size_t)((node0 << 4) + row) * EF;
            #pragma unroll
            for (int k0 = 0; k0 < 2; k0++)
                *(uint4*)(A_s + ((wv * K0C + 4 + k0) * 64 + lane) * 8) =
                    *(const uint4*)(efp + k0 * 32 + q * 8);
        } else {
            for (int c = t; c < 64 * EF; c += 256) {
                int rr = c >> 6, col = c & 63;
                float a = be[col];
                const float* er = edge_fea + (size_t)(node0 * Mm + rr) * OEF;
                #pragma unroll
                for (int i = 0; i < OEF; i++) a = fmaf(er[i], WeT[i * EF + col], a);
                int mt = rr >> 4, l16 = rr & 15;
                int k0 = 4 + (col >> 5), qq = (col >> 3) & 3, jj = col & 7;
                A_s[((mt * K0C + k0) * 64 + qq * 16 + l16) * 8 + jj] = to_bf16(a);
            }
        }
    }
    __syncthreads();

    // ---- self-term S via MFMA (C rows 0..3 hold S[node 0..3]; rows 4..15 dup, unused)
    // tiles this wave needs: F: 2wv, 2wv+1 ; C: 2wv+8, 2wv+9
    f32x4 sv[4];
    #pragma unroll
    for (int c = 0; c < 4; c++) {
        int tile = 2 * wv + (c & 1) + ((c >> 1) << 3);
        float bv = bias[tile * 16 + ln16];
        sv[c] = (f32x4){bv, bv, bv, bv};
    }
    #pragma unroll
    for (int k0 = 0; k0 < 4; k0++) {
        short8 afs = *(const short8*)(A_sf + (k0 * 64 + lane) * 8);
        #pragma unroll
        for (int c = 0; c < 4; c++) {
            int tile = 2 * wv + (c & 1) + ((c >> 1) << 3);
            short8 bws = *(const short8*)(Wsb + ((size_t)(tile * 4 + k0) << 9) + (lane << 3));
            sv[c] = __builtin_amdgcn_mfma_f32_16x16x32_bf16(afs, bws, sv[c], 0, 0, 0);
        }
    }

    // broadcast S[mt][col] (held at lane ln16, q=0, reg mt) to all lanes -> acc init
    f32x4 accF[4][2], accC[4][2];
    #pragma unroll
    for (int mt = 0; mt < 4; mt++) {
        #pragma unroll
        for (int p = 0; p < 2; p++) {
            float vF = __shfl(sv[p][mt], ln16);
            float vC = __shfl(sv[2 + p][mt], ln16);
            accF[mt][p] = (f32x4){vF, vF, vF, vF};
            accC[mt][p] = (f32x4){vC, vC, vC, vC};
        }
    }

    // ---- main K-loop (K=192): gather + edge
    const __hip_bfloat16* WF0 = Wb + ((size_t)(2 * wv) * (K0C * 512)) + (lane << 3);
    const __hip_bfloat16* WF1 = WF0 + K0C * 512;
    const __hip_bfloat16* WC0 = WF0 + 8 * (K0C * 512);
    const __hip_bfloat16* WC1 = WC0 + K0C * 512;

    #pragma unroll
    for (int k0 = 0; k0 < K0C; k0++) {
        short8 cF0 = *(const short8*)(WF0 + k0 * 512);
        short8 cF1 = *(const short8*)(WF1 + k0 * 512);
        short8 cC0 = *(const short8*)(WC0 + k0 * 512);
        short8 cC1 = *(const short8*)(WC1 + k0 * 512);
        short8 af[4];
        #pragma unroll
        for (int mt = 0; mt < 4; mt++)
            af[mt] = *(const short8*)(A_s + ((mt * K0C + k0) * 64 + lane) * 8);
        #pragma unroll
        for (int mt = 0; mt < 4; mt++) {
            accF[mt][0] = __builtin_amdgcn_mfma_f32_16x16x32_bf16(af[mt], cF0, accF[mt][0], 0, 0, 0);
            accF[mt][1] = __builtin_amdgcn_mfma_f32_16x16x32_bf16(af[mt], cF1, accF[mt][1], 0, 0, 0);
            accC[mt][0] = __builtin_amdgcn_mfma_f32_16x16x32_bf16(af[mt], cC0, accC[mt][0], 0, 0, 0);
            accC[mt][1] = __builtin_amdgcn_mfma_f32_16x16x32_bf16(af[mt], cC1, accC[mt][1], 0, 0, 0);
        }
    }

    // epilogue
    const float alpha = *palpha;
    #pragma unroll
    for (int mt = 0; mt < 4; mt++) {
        const int gnode = node0 + mt;
        unsigned mbits = (unsigned)(mball >> (mt * 16 + q * 4)) & 0xFu;
        #pragma unroll
        for (int p = 0; p < 2; p++) {
            float partial = 0.0f;
            #pragma unroll
            for (int r = 0; r < 4; r++) {
                bool msk = (mbits >> r) & 1u;
                float f = sigmoidf_(accF[mt][p][r]);
                float c = softplusf_(accC[mt][p][r]);
                partial += msk ? f * c : 0.0f;
            }
            partial += __shfl_xor(partial, 16);
            partial += __shfl_xor(partial, 32);
            if (q == 0) {
                int col = (2 * wv + p) * 16 + ln16;
                float self = __bfloat162float(nf_in[(size_t)gnode * NF + col]);
                nf_out[(size_t)gnode * NF + col] = to_bf16(softplusf_(fmaf(alpha, self, partial)));
            }
        }
    }
}

// ---------- final linear (MFMA): out[:, :, 0:64] = nf3 @ Wf^T + bf ----------
__global__ __launch_bounds__(256) void k_final_mfma(
    const __hip_bfloat16* __restrict__ nf, const __hip_bfloat16* __restrict__ Wfb,
    const float* __restrict__ bfv, float* __restrict__ out,
    __hip_bfloat16* __restrict__ XT)
{
    __shared__ __align__(16) __hip_bfloat16 A_s[16 * 512];
    const int node0 = blockIdx.x * 64;
    const int bloc = node0 >> 8;
    const int t = threadIdx.x;
    const int wv = t >> 6, lane = t & 63;
    const int q = lane >> 4, ln16 = lane & 15;

    const __hip_bfloat16* rowp = nf + (size_t)(node0 + (wv << 4) + ln16) * NF;
    #pragma unroll
    for (int k0 = 0; k0 < 4; k0++)
        *(uint4*)(A_s + ((wv * 4 + k0) * 64 + lane) * 8) =
            *(const uint4*)(rowp + k0 * 32 + q * 8);
    __syncthreads();

    short8 bw[4];
    #pragma unroll
    for (int k0 = 0; k0 < 4; k0++)
        bw[k0] = *(const short8*)(Wfb + ((size_t)(wv * 4 + k0) * 64 + lane) * 8);

    float bv = bfv[wv * 16 + ln16];
    f32x4 acc[4];
    #pragma unroll
    for (int mt = 0; mt < 4; mt++) acc[mt] = (f32x4){bv, bv, bv, bv};

    #pragma unroll
    for (int k0 = 0; k0 < 4; k0++) {
        short8 af[4];
        #pragma unroll
        for (int mt = 0; mt < 4; mt++)
            af[mt] = *(const short8*)(A_s + ((mt * 4 + k0) * 64 + lane) * 8);
        #pragma unroll
        for (int mt = 0; mt < 4; mt++)
            acc[mt] = __builtin_amdgcn_mfma_f32_16x16x32_bf16(af[mt], bw[k0], acc[mt], 0, 0, 0);
    }

    const int col = (wv << 4) + ln16;
    #pragma unroll
    for (int mt = 0; mt < 4; mt++)
        #pragma unroll
        for (int r = 0; r < 4; r++) {
            int row = mt * 16 + q * 4 + r;
            float v = acc[mt][r];
            out[(size_t)(node0 + row) * FINAL + col] = v;
            XT[(size_t)(bloc * 64 + col) * 256 + (node0 & 255) + row] = to_bf16(v);
        }
}

// ---------- node1 (MFMA): out[:, :, 64:128] = DA @ nff per batch ----------
__global__ __launch_bounds__(256) void k_node1_mfma(
    const __hip_bfloat16* __restrict__ DAf,   // A-fragment order [16][8][64][8]
    const __hip_bfloat16* __restrict__ XT,    // [B][64 f][256 j] bf16
    float* __restrict__ out)
{
    __shared__ __align__(16) __hip_bfloat16 B_s[32 * 512];
    const int blk = blockIdx.x;
    const int b = blk >> 2, i0 = (blk & 3) * 64;
    const int t = threadIdx.x;
    const int wv = t >> 6, lane = t & 63;
    const int q = lane >> 4, ln16 = lane & 15;

    const __hip_bfloat16* xrow = XT + (size_t)(b * 64 + (wv << 4) + ln16) * 256;
    #pragma unroll
    for (int k0 = 0; k0 < 8; k0++)
        *(uint4*)(B_s + ((wv * 8 + k0) * 64 + lane) * 8) =
            *(const uint4*)(xrow + k0 * 32 + q * 8);
    __syncthreads();

    f32x4 acc[4];
    #pragma unroll
    for (int mt = 0; mt < 4; mt++) acc[mt] = (f32x4){0.f, 0.f, 0.f, 0.f};

    #pragma unroll
    for (int k0 = 0; k0 < 8; k0++) {
        short8 bfr = *(const short8*)(B_s + ((wv * 8 + k0) * 64 + lane) * 8);
        short8 af[4];
        #pragma unroll
        for (int mt = 0; mt < 4; mt++)
            af[mt] = *(const short8*)(DAf + (size_t)(((i0 >> 4) + mt) * 8 + k0) * 512 + (lane << 3));
        #pragma unroll
        for (int mt = 0; mt < 4; mt++)
            acc[mt] = __builtin_amdgcn_mfma_f32_16x16x32_bf16(af[mt], bfr, acc[mt], 0, 0, 0);
    }

    #pragma unroll
    for (int mt = 0; mt < 4; mt++)
        #pragma unroll
        for (int r = 0; r < 4; r++) {
            int i = i0 + mt * 16 + q * 4 + r;
            out[(size_t)((b << 8) + i) * FINAL + 64 + (wv << 4) + ln16] = acc[mt][r];
        }
}

extern "C" void kernel_launch(void* const* d_in, const int* in_sizes, int n_in,
                              void* d_out, int out_size, void* d_ws, size_t ws_size,
                              hipStream_t stream)
{
    const float* node_fea = (const float*)d_in[0];
    const float* edge_fea = (const float*)d_in[1];
    const int*   eidx     = (const int*)  d_in[2];
    const float* dis      = (const float*)d_in[3];
    const float* Wn = (const float*)d_in[4];
    const float* bn = (const float*)d_in[5];
    const float* We = (const float*)d_in[6];
    const float* be = (const float*)d_in[7];
    const float* W1 = (const float*)d_in[8];
    const float* b1 = (const float*)d_in[9];
    const float* a1 = (const float*)d_in[10];
    const float* W2 = (const float*)d_in[11];
    const float* b2 = (const float*)d_in[12];
    const float* a2 = (const float*)d_in[13];
    const float* W3 = (const float*)d_in[14];
    const float* b3 = (const float*)d_in[15];
    const float* a3 = (const float*)d_in[16];
    const float* Wf = (const float*)d_in[17];
    const float* bf = (const float*)d_in[18];
    const float* DAw = (const float*)d_in[19];
    const float* DAb = (const float*)d_in[20];
    float* out = (float*)d_out;

    // workspace layout (bytes, 256-aligned blocks)
    char* base = (char*)d_ws;
    size_t off = 0;
    auto alloc = [&](size_t bytes) { char* p = base + off; off = (off + bytes + 255) & ~(size_t)255; return p; };
    __hip_bfloat16* nfA = (__hip_bfloat16*)alloc((size_t)Bb * Nn * NF * 2);
    __hip_bfloat16* nfB = (__hip_bfloat16*)alloc((size_t)Bb * Nn * NF * 2);
    __hip_bfloat16* W1b = (__hip_bfloat16*)alloc((size_t)SZ_WB * 2);
    __hip_bfloat16* W2b = (__hip_bfloat16*)alloc((size_t)SZ_WB * 2);
    __hip_bfloat16* W3b = (__hip_bfloat16*)alloc((size_t)SZ_WB * 2);
    __hip_bfloat16* W1s = (__hip_bfloat16*)alloc((size_t)SZ_WS * 2);
    __hip_bfloat16* W2s = (__hip_bfloat16*)alloc((size_t)SZ_WS * 2);
    __hip_bfloat16* W3s = (__hip_bfloat16*)alloc((size_t)SZ_WS * 2);
    float* WeT = (float*)alloc((size_t)OEF * EF * 4);
    __hip_bfloat16* DAf = (__hip_bfloat16*)alloc((size_t)Nn * Nn * 2);
    __hip_bfloat16* Wnb = (__hip_bfloat16*)alloc((size_t)SZ_WNB * 2);
    __hip_bfloat16* Web = (__hip_bfloat16*)alloc((size_t)SZ_WEB * 2);
    __hip_bfloat16* Wfb = (__hip_bfloat16*)alloc((size_t)SZ_WFB * 2);
    __hip_bfloat16* XT  = (__hip_bfloat16*)alloc((size_t)Bb * 64 * Nn * 2);
    __hip_bfloat16* efb = (__hip_bfloat16*)alloc((size_t)Bb * Nn * Mm * EF * 2);    // 33.5 MB
    const bool precomp = (ws_size >= off);

    hipLaunchKernelGGL(k_prep, dim3((PREP_TOTAL + 255) / 256), dim3(256), 0, stream,
                       We, W1, W2, W3, Wn, Wf, dis, DAw, DAb,
                       WeT, W1b, W2b, W3b, W1s, W2s, W3s, Wnb, Web, Wfb, DAf);

    hipLaunchKernelGGL(k_embed_all, dim3(precomp ? (256 + Bb * Nn * Mm / 64) : 256), dim3(256), 0, stream,
                       node_fea, Wnb, bn, nfA, edge_fea, Web, be, efb);

    if (precomp) {
        hipLaunchKernelGGL((k_conv_mfma<true>), dim3(Bb * Nn / 4), dim3(256), 0, stream,
                           nfA, edge_fea, efb, eidx, WeT, be, W1b, W1s, b1, a1, nfB);
        hipLaunchKernelGGL((k_conv_mfma<true>), dim3(Bb * Nn / 4), dim3(256), 0, stream,
                           nfB, edge_fea, efb, eidx, WeT, be, W2b, W2s, b2, a2, nfA);
        hipLaunchKernelGGL((k_conv_mfma<true>), dim3(Bb * Nn / 4), dim3(256), 0, stream,
                           nfA, edge_fea, efb, eidx, WeT, be, W3b, W3s, b3, a3, nfB);
    } else {
        hipLaunchKernelGGL((k_conv_mfma<false>), dim3(Bb * Nn / 4), dim3(256), 0, stream,
                           nfA, edge_fea, efb, eidx, WeT, be, W1b, W1s, b1, a1, nfB);
        hipLaunchKernelGGL((k_conv_mfma<false>), dim3(Bb * Nn / 4), dim3(256), 0, stream,
                           nfB, edge_fea, efb, eidx, WeT, be, W2b, W2s, b2, a2, nfA);
        hipLaunchKernelGGL((k_conv_mfma<false>), dim3(Bb * Nn / 4), dim3(256), 0, stream,
                           nfA, edge_fea, efb, eidx, WeT, be, W3b, W3s, b3, a3, nfB);
    }

    hipLaunchKernelGGL(k_final_mfma, dim3(Bb * Nn / 64), dim3(256), 0, stream, nfB, Wfb, bf, out, XT);
    hipLaunchKernelGGL(k_node1_mfma, dim3(Bb * 4), dim3(256), 0, stream, DAf, XT, out);
}

// Round 14
// 300.649 us; speedup vs baseline: 1.3312x; 1.0114x over previous
//
#include <hip/hip_runtime.h>
#include <hip/hip_bf16.h>
#include <math.h>

#define Bb   64
#define Nn   256
#define Mm   16
#define ONF  92
#define OEF  41
#define NF   128
#define EF   64
#define KDIM 320   // 2*NF + EF
#define ODIM 256   // 2*NF
#define FINAL 128
#define K0C  6     // conv K-chunks (K=192: gather 128 + edge 64)

#define LOG2E_F 1.44269504088896f
#define LN2_F   0.6931471805599453f

typedef __attribute__((ext_vector_type(8))) short short8;
typedef __attribute__((ext_vector_type(4))) float f32x4;

__device__ __forceinline__ float sigmoidf_(float x) {
    float e = __expf(-x);
    return __builtin_amdgcn_rcpf(1.0f + e);
}
__device__ __forceinline__ float softplusf_(float x) {
    return fmaxf(x, 0.0f) + __logf(1.0f + __expf(-fabsf(x)));
}
__device__ __forceinline__ __hip_bfloat16 to_bf16(float x) { return __float2bfloat16(x); }

// ---------- mega-prep: all weight swizzles + WeT + DA in ONE launch ----------
// scale: gate weights are pre-scaled by log2(e) so conv epilogue runs in
// log2-domain (raw v_exp/v_log, no per-element ln2/log2e muls).
__device__ __forceinline__ void swz(const float* __restrict__ in, __hip_bfloat16* __restrict__ out,
                                    int t, int Itot, int koff, int Kuse, int K0, float scale)
{
    int j = t & 7;
    int u = t >> 3;
    int lane = u & 63;
    int ln16 = lane & 15, q = lane >> 4;
    int v = u >> 6;
    int k0 = v % K0, tile = v / K0;
    int n = tile * 16 + ln16, k = k0 * 32 + q * 8 + j;
    out[t] = (k < Kuse) ? to_bf16(scale * in[(size_t)n * Itot + koff + k]) : to_bf16(0.0f);
}

#define SZ_WET (OEF * EF)          // 2624
#define SZ_WB  (16 * K0C * 512)    // 49152
#define SZ_WS  (16 * 4 * 512)      // 32768
#define SZ_WNB ((NF / 16) * 3 * 512)
#define SZ_WEB ((EF / 16) * 2 * 512)
#define SZ_WFB ((64 / 16) * 4 * 512)
#define SZ_DA  (Nn * Nn)
#define PREP_TOTAL (SZ_WET + 3 * SZ_WB + 3 * SZ_WS + SZ_WNB + SZ_WEB + SZ_WFB + SZ_DA)

__global__ __launch_bounds__(256) void k_prep(
    const float* __restrict__ We, const float* __restrict__ W1,
    const float* __restrict__ W2, const float* __restrict__ W3,
    const float* __restrict__ Wn, const float* __restrict__ Wf,
    const float* __restrict__ dis, const float* __restrict__ pw, const float* __restrict__ pb,
    float* __restrict__ WeT,
    __hip_bfloat16* __restrict__ W1b, __hip_bfloat16* __restrict__ W2b, __hip_bfloat16* __restrict__ W3b,
    __hip_bfloat16* __restrict__ W1s, __hip_bfloat16* __restrict__ W2s, __hip_bfloat16* __restrict__ W3s,
    __hip_bfloat16* __restrict__ Wnb, __hip_bfloat16* __restrict__ Web, __hip_bfloat16* __restrict__ Wfb,
    __hip_bfloat16* __restrict__ DAf)
{
    int t = blockIdx.x * 256 + threadIdx.x;
    if (t < SZ_WET) {
        int o = t / OEF, i = t - o * OEF;
        WeT[i * EF + o] = We[t];
        return;
    }
    t -= SZ_WET;
    if (t < SZ_WB) { swz(W1, W1b, t, KDIM, NF, 192, K0C, LOG2E_F); return; }
    t -= SZ_WB;
    if (t < SZ_WB) { swz(W2, W2b, t, KDIM, NF, 192, K0C, LOG2E_F); return; }
    t -= SZ_WB;
    if (t < SZ_WB) { swz(W3, W3b, t, KDIM, NF, 192, K0C, LOG2E_F); return; }
    t -= SZ_WB;
    if (t < SZ_WS) { swz(W1, W1s, t, KDIM, 0, NF, 4, LOG2E_F); return; }
    t -= SZ_WS;
    if (t < SZ_WS) { swz(W2, W2s, t, KDIM, 0, NF, 4, LOG2E_F); return; }
    t -= SZ_WS;
    if (t < SZ_WS) { swz(W3, W3s, t, KDIM, 0, NF, 4, LOG2E_F); return; }
    t -= SZ_WS;
    if (t < SZ_WNB) { swz(Wn, Wnb, t, ONF, 0, ONF, 3, 1.0f); return; }
    t -= SZ_WNB;
    if (t < SZ_WEB) { swz(We, Web, t, OEF, 0, OEF, 2, 1.0f); return; }
    t -= SZ_WEB;
    if (t < SZ_WFB) { swz(Wf, Wfb, t, NF, 0, NF, 4, 1.0f); return; }
    t -= SZ_WFB;
    if (t < SZ_DA) {
        int i = t >> 8, jx = t & 255;
        float v = sigmoidf_(fmaf(*pw, dis[t], *pb));
        int itile = i >> 4, ln16 = i & 15;
        int k0 = jx >> 5, q = (jx >> 3) & 3, jj = jx & 7;
        DAf[(size_t)((((itile * 8 + k0) << 6) + (q << 4) + ln16)) * 8 + jj] = to_bf16(v);
    }
}

// ---------- generic MFMA embed body ----------
template<int KIN, int K0, int NCOLS>
__device__ __forceinline__ void emb_body(
    int bid, const float* __restrict__ X, const __hip_bfloat16* __restrict__ Bswz,
    const float* __restrict__ bias, __hip_bfloat16* __restrict__ Y,
    __hip_bfloat16* A_s, __hip_bfloat16* O_s)
{
    constexpr int KP = K0 * 32;
    constexpr int TPW = NCOLS / 64;
    constexpr int OLD = NCOLS + 24;

    const int row0 = bid * 64;
    const int t = threadIdx.x;

    {
        const float4* Xb = (const float4*)(X + (size_t)row0 * KIN);
        constexpr int NV = (64 * KIN) / 4;
        for (int c = t; c < NV; c += 256) {
            float4 v = Xb[c];
            int flat = c * 4;
            #pragma unroll
            for (int e = 0; e < 4; e++) {
                int f = flat + e;
                int row = f / KIN, k = f - row * KIN;
                int mt = row >> 4, ln16 = row & 15;
                int k0 = k >> 5, q = (k >> 3) & 3, j = k & 7;
                float vv = (e == 0) ? v.x : (e == 1) ? v.y : (e == 2) ? v.z : v.w;
                A_s[(((mt * K0 + k0) << 6) + (q << 4) + ln16) * 8 + j] = to_bf16(vv);
            }
        }
        constexpr int PAD = KP - KIN;
        for (int c = t; c < 64 * PAD; c += 256) {
            int row = c / PAD, k = KIN + (c - row * PAD);
            int mt = row >> 4, ln16 = row & 15;
            int k0 = k >> 5, q = (k >> 3) & 3, j = k & 7;
            A_s[(((mt * K0 + k0) << 6) + (q << 4) + ln16) * 8 + j] = to_bf16(0.0f);
        }
    }
    __syncthreads();

    const int wv = t >> 6, lane = t & 63;
    const int q = lane >> 4, ln16 = lane & 15;

    f32x4 acc[4][TPW];
    #pragma unroll
    for (int p = 0; p < TPW; p++) {
        float bv = bias[(wv * TPW + p) * 16 + ln16];
        #pragma unroll
        for (int mt = 0; mt < 4; mt++) acc[mt][p] = (f32x4){bv, bv, bv, bv};
    }

    short8 bw[TPW][K0];
    #pragma unroll
    for (int p = 0; p < TPW; p++)
        #pragma unroll
        for (int k0 = 0; k0 < K0; k0++)
            bw[p][k0] = *(const short8*)(Bswz + ((size_t)((wv * TPW + p) * K0 + k0) << 9) + (lane << 3));

    #pragma unroll
    for (int k0 = 0; k0 < K0; k0++) {
        short8 af[4];
        #pragma unroll
        for (int mt = 0; mt < 4; mt++)
            af[mt] = *(const short8*)(A_s + (((mt * K0 + k0) << 6) + lane) * 8);
        #pragma unroll
        for (int mt = 0; mt < 4; mt++)
            #pragma unroll
            for (int p = 0; p < TPW; p++)
                acc[mt][p] = __builtin_amdgcn_mfma_f32_16x16x32_bf16(af[mt], bw[p][k0], acc[mt][p], 0, 0, 0);
    }

    #pragma unroll
    for (int mt = 0; mt < 4; mt++)
        #pragma unroll
        for (int p = 0; p < TPW; p++) {
            int col = (wv * TPW + p) * 16 + ln16;
            #pragma unroll
            for (int r = 0; r < 4; r++)
                O_s[(mt * 16 + q * 4 + r) * OLD + col] = to_bf16(acc[mt][p][r]);
        }
    __syncthreads();
    constexpr int CH = NCOLS / 8;
    for (int c = t; c < 64 * CH; c += 256) {
        int row = c / CH, ch = c - row * CH;
        *(uint4*)(Y + (size_t)(row0 + row) * NCOLS + ch * 8) =
            *(const uint4*)(O_s + row * OLD + ch * 8);
    }
}

// blocks [0,256): node embed; [256, 256+4096): edge embed
__global__ __launch_bounds__(256) void k_embed_all(
    const float* __restrict__ node_fea, const __hip_bfloat16* __restrict__ Wnb,
    const float* __restrict__ bn, __hip_bfloat16* __restrict__ nf0,
    const float* __restrict__ edge_fea, const __hip_bfloat16* __restrict__ Web,
    const float* __restrict__ be, __hip_bfloat16* __restrict__ efb)
{
    __shared__ __align__(16) __hip_bfloat16 A_s[4 * 3 * 512];
    __shared__ __align__(16) __hip_bfloat16 O_s[64 * (NF + 24)];
    if (blockIdx.x < 256)
        emb_body<ONF, 3, NF>(blockIdx.x, node_fea, Wnb, bn, nf0, A_s, O_s);
    else
        emb_body<OEF, 2, EF>(blockIdx.x - 256, edge_fea, Web, be, efb, A_s, O_s);
}

// ---------- conv layer: MFMA, K=192, self-term fused, log2-domain epilogue ----------
template<bool PRECOMP>
__global__ __launch_bounds__(256, 3) void k_conv_mfma(
    const __hip_bfloat16* __restrict__ nf_in,   // [B*N][NF] bf16
    const float* __restrict__ edge_fea,         // [B*N*M][OEF] f32  (PRECOMP=false)
    const __hip_bfloat16* __restrict__ ef_bf,   // [B*N*M][EF] bf16  (PRECOMP=true)
    const int*   __restrict__ eidx,             // [B*N][M]
    const float* __restrict__ WeT,              // [OEF][EF] f32     (PRECOMP=false)
    const float* __restrict__ be,               // [EF]              (PRECOMP=false)
    const __hip_bfloat16* __restrict__ Wb,      // [16][K0C][64][8] (log2e*W[:,128:320])
    const __hip_bfloat16* __restrict__ Wsb,     // [16][4][64][8]   (log2e*W[:,0:128])
    const float* __restrict__ bias,             // [ODIM] (raw; scaled in-kernel)
    const float* __restrict__ palpha,
    __hip_bfloat16* __restrict__ nf_out)        // [B*N][NF] bf16
{
    __shared__ __align__(16) __hip_bfloat16 A_s[4 * K0C * 512];   // 24576 B
    __shared__ __align__(16) __hip_bfloat16 A_sf[4 * 512];        //  4096 B (self rows 0..3)

    const int node0 = blockIdx.x * 4;
    const int b = node0 >> 8;
    const int t = threadIdx.x;
    const int wv = t >> 6, lane = t & 63;
    const int q = lane >> 4, ln16 = lane & 15;
    const int row = (wv << 4) + ln16;                 // this lane's A-tile row

    const int myidx = eidx[node0 * Mm + row];
    const unsigned long long mball = __ballot(eidx[node0 * Mm + lane] >= 0);

    // prefetch the epilogue self-read (issued now, used at the very end;
    // same addr across q -> L1 broadcast; +8 VGPRs, slack exists at 3 waves/EU)
    float selfv[8];
    #pragma unroll
    for (int mt = 0; mt < 4; mt++)
        #pragma unroll
        for (int p = 0; p < 2; p++)
            selfv[mt * 2 + p] =
                __bfloat162float(nf_in[(size_t)(node0 + mt) * NF + (2 * wv + p) * 16 + ln16]);

    // stage A (fragment order; conflict-free base + lane*16)
    {
        int j = myidx < 0 ? 0 : myidx;
        const __hip_bfloat16* gathp = nf_in + (size_t)((b << 8) + j) * NF;
        #pragma unroll
        for (int k0 = 0; k0 < 4; k0++)
            *(uint4*)(A_s + ((wv * K0C + k0) * 64 + lane) * 8) =
                *(const uint4*)(gathp + k0 * 32 + q * 8);
        // self rows, conflict-free: wave wv stages slot wv; rows m=4..15 become
        // copies of m&3 (harmless — self-MFMA rows 4..15 are discarded).
        *(uint4*)(A_sf + (wv * 64 + lane) * 8) =
            *(const uint4*)(nf_in + (size_t)(node0 + (ln16 & 3)) * NF + wv * 32 + q * 8);
        if (PRECOMP) {
            const __hip_bfloat16* efp = ef_bf + (size_t)((node0 << 4) + row) * EF;
            #pragma unroll
            for (int k0 = 0; k0 < 2; k0++)
                *(uint4*)(A_s + ((wv * K0C + 4 + k0) * 64 + lane) * 8) =
                    *(const uint4*)(efp + k0 * 32 + q * 8);
        } else {
            for (int c = t; c < 64 * EF; c += 256) {
                int rr = c >> 6, col = c & 63;
                float a = be[col];
                const float* er = edge_fea + (size_t)(node0 * Mm + rr) * OEF;
                #pragma unroll
                for (int i = 0; i < OEF; i++) a = fmaf(er[i], WeT[i * EF + col], a);
                int mt = rr >> 4, l16 = rr & 15;
                int k0 = 4 + (col >> 5), qq = (col >> 3) & 3, jj = col & 7;
                A_s[((mt * K0C + k0) * 64 + qq * 16 + l16) * 8 + jj] = to_bf16(a);
            }
        }
    }
    __syncthreads();

    // ---- self-term S via MFMA (log2-domain: Wsb pre-scaled, bias scaled here)
    f32x4 sv[4];
    #pragma unroll
    for (int c = 0; c < 4; c++) {
        int tile = 2 * wv + (c & 1) + ((c >> 1) << 3);
        float bv = bias[tile * 16 + ln16] * LOG2E_F;
        sv[c] = (f32x4){bv, bv, bv, bv};
    }
    #pragma unroll
    for (int k0 = 0; k0 < 4; k0++) {
        short8 afs = *(const short8*)(A_sf + (k0 * 64 + lane) * 8);
        #pragma unroll
        for (int c = 0; c < 4; c++) {
            int tile = 2 * wv + (c & 1) + ((c >> 1) << 3);
            short8 bws = *(const short8*)(Wsb + ((size_t)(tile * 4 + k0) << 9) + (lane << 3));
            sv[c] = __builtin_amdgcn_mfma_f32_16x16x32_bf16(afs, bws, sv[c], 0, 0, 0);
        }
    }

    // broadcast S[mt][col] (held at lane ln16, q=0, reg mt) to all lanes -> acc init
    f32x4 accF[4][2], accC[4][2];
    #pragma unroll
    for (int mt = 0; mt < 4; mt++) {
        #pragma unroll
        for (int p = 0; p < 2; p++) {
            float vF = __shfl(sv[p][mt], ln16);
            float vC = __shfl(sv[2 + p][mt], ln16);
            accF[mt][p] = (f32x4){vF, vF, vF, vF};
            accC[mt][p] = (f32x4){vC, vC, vC, vC};
        }
    }

    // ---- main K-loop (K=192): gather + edge
    const __hip_bfloat16* WF0 = Wb + ((size_t)(2 * wv) * (K0C * 512)) + (lane << 3);
    const __hip_bfloat16* WF1 = WF0 + K0C * 512;
    const __hip_bfloat16* WC0 = WF0 + 8 * (K0C * 512);
    const __hip_bfloat16* WC1 = WC0 + K0C * 512;

    #pragma unroll
    for (int k0 = 0; k0 < K0C; k0++) {
        short8 cF0 = *(const short8*)(WF0 + k0 * 512);
        short8 cF1 = *(const short8*)(WF1 + k0 * 512);
        short8 cC0 = *(const short8*)(WC0 + k0 * 512);
        short8 cC1 = *(const short8*)(WC1 + k0 * 512);
        short8 af[4];
        #pragma unroll
        for (int mt = 0; mt < 4; mt++)
            af[mt] = *(const short8*)(A_s + ((mt * K0C + k0) * 64 + lane) * 8);
        #pragma unroll
        for (int mt = 0; mt < 4; mt++) {
            accF[mt][0] = __builtin_amdgcn_mfma_f32_16x16x32_bf16(af[mt], cF0, accF[mt][0], 0, 0, 0);
            accF[mt][1] = __builtin_amdgcn_mfma_f32_16x16x32_bf16(af[mt], cF1, accF[mt][1], 0, 0, 0);
            accC[mt][0] = __builtin_amdgcn_mfma_f32_16x16x32_bf16(af[mt], cC0, accC[mt][0], 0, 0, 0);
            accC[mt][1] = __builtin_amdgcn_mfma_f32_16x16x32_bf16(af[mt], cC1, accC[mt][1], 0, 0, 0);
        }
    }

    // ---- epilogue (log2-domain: gated values are log2e * natural)
    // sigmoid(f) = rcp(1 + 2^(-f'));  softplus(c) = ln2*[max(c',0)+log2(1+2^(-|c'|))]
    // ln2 factored out of the m-sum; applied once before the final softplus.
    const float alpha = *palpha;
    #pragma unroll
    for (int mt = 0; mt < 4; mt++) {
        const int gnode = node0 + mt;
        unsigned mbits = (unsigned)(mball >> (mt * 16 + q * 4)) & 0xFu;
        #pragma unroll
        for (int p = 0; p < 2; p++) {
            float partial = 0.0f;
            #pragma unroll
            for (int r = 0; r < 4; r++) {
                bool msk = (mbits >> r) & 1u;
                float f2 = accF[mt][p][r];
                float c2 = accC[mt][p][r];
                float sig = __builtin_amdgcn_rcpf(1.0f + __builtin_amdgcn_exp2f(-f2));
                float sp2 = fmaxf(c2, 0.0f) +
                            __builtin_amdgcn_logf(1.0f + __builtin_amdgcn_exp2f(-fabsf(c2)));
                partial += msk ? sig * sp2 : 0.0f;
            }
            partial += __shfl_xor(partial, 16);
            partial += __shfl_xor(partial, 32);
            if (q == 0) {
                int col = (2 * wv + p) * 16 + ln16;
                nf_out[(size_t)gnode * NF + col] =
                    to_bf16(softplusf_(fmaf(alpha, selfv[mt * 2 + p], LN2_F * partial)));
            }
        }
    }
}

// ---------- final linear (MFMA): out[:, :, 0:64] = nf3 @ Wf^T + bf ----------
__global__ __launch_bounds__(256) void k_final_mfma(
    const __hip_bfloat16* __restrict__ nf, const __hip_bfloat16* __restrict__ Wfb,
    const float* __restrict__ bfv, float* __restrict__ out,
    __hip_bfloat16* __restrict__ XT)
{
    __shared__ __align__(16) __hip_bfloat16 A_s[16 * 512];
    const int node0 = blockIdx.x * 64;
    const int bloc = node0 >> 8;
    const int t = threadIdx.x;
    const int wv = t >> 6, lane = t & 63;
    const int q = lane >> 4, ln16 = lane & 15;

    const __hip_bfloat16* rowp = nf + (size_t)(node0 + (wv << 4) + ln16) * NF;
    #pragma unroll
    for (int k0 = 0; k0 < 4; k0++)
        *(uint4*)(A_s + ((wv * 4 + k0) * 64 + lane) * 8) =
            *(const uint4*)(rowp + k0 * 32 + q * 8);
    __syncthreads();

    short8 bw[4];
    #pragma unroll
    for (int k0 = 0; k0 < 4; k0++)
        bw[k0] = *(const short8*)(Wfb + ((size_t)(wv * 4 + k0) * 64 + lane) * 8);

    float bv = bfv[wv * 16 + ln16];
    f32x4 acc[4];
    #pragma unroll
    for (int mt = 0; mt < 4; mt++) acc[mt] = (f32x4){bv, bv, bv, bv};

    #pragma unroll
    for (int k0 = 0; k0 < 4; k0++) {
        short8 af[4];
        #pragma unroll
        for (int mt = 0; mt < 4; mt++)
            af[mt] = *(const short8*)(A_s + ((mt * 4 + k0) * 64 + lane) * 8);
        #pragma unroll
        for (int mt = 0; mt < 4; mt++)
            acc[mt] = __builtin_amdgcn_mfma_f32_16x16x32_bf16(af[mt], bw[k0], acc[mt], 0, 0, 0);
    }

    const int col = (wv << 4) + ln16;
    #pragma unroll
    for (int mt = 0; mt < 4; mt++)
        #pragma unroll
        for (int r = 0; r < 4; r++) {
            int row = mt * 16 + q * 4 + r;
            float v = acc[mt][r];
            out[(size_t)(node0 + row) * FINAL + col] = v;
            XT[(size_t)(bloc * 64 + col) * 256 + (node0 & 255) + row] = to_bf16(v);
        }
}

// ---------- node1 (MFMA): out[:, :, 64:128] = DA @ nff per batch ----------
__global__ __launch_bounds__(256) void k_node1_mfma(
    const __hip_bfloat16* __restrict__ DAf,   // A-fragment order [16][8][64][8]
    const __hip_bfloat16* __restrict__ XT,    // [B][64 f][256 j] bf16
    float* __restrict__ out)
{
    __shared__ __align__(16) __hip_bfloat16 B_s[32 * 512];
    const int blk = blockIdx.x;
    const int b = blk >> 2, i0 = (blk & 3) * 64;
    const int t = threadIdx.x;
    const int wv = t >> 6, lane = t & 63;
    const int q = lane >> 4, ln16 = lane & 15;

    const __hip_bfloat16* xrow = XT + (size_t)(b * 64 + (wv << 4) + ln16) * 256;
    #pragma unroll
    for (int k0 = 0; k0 < 8; k0++)
        *(uint4*)(B_s + ((wv * 8 + k0) * 64 + lane) * 8) =
            *(const uint4*)(xrow + k0 * 32 + q * 8);
    __syncthreads();

    f32x4 acc[4];
    #pragma unroll
    for (int mt = 0; mt < 4; mt++) acc[mt] = (f32x4){0.f, 0.f, 0.f, 0.f};

    #pragma unroll
    for (int k0 = 0; k0 < 8; k0++) {
        short8 bfr = *(const short8*)(B_s + ((wv * 8 + k0) * 64 + lane) * 8);
        short8 af[4];
        #pragma unroll
        for (int mt = 0; mt < 4; mt++)
            af[mt] = *(const short8*)(DAf + (size_t)(((i0 >> 4) + mt) * 8 + k0) * 512 + (lane << 3));
        #pragma unroll
        for (int mt = 0; mt < 4; mt++)
            acc[mt] = __builtin_amdgcn_mfma_f32_16x16x32_bf16(af[mt], bfr, acc[mt], 0, 0, 0);
    }

    #pragma unroll
    for (int mt = 0; mt < 4; mt++)
        #pragma unroll
        for (int r = 0; r < 4; r++) {
            int i = i0 + mt * 16 + q * 4 + r;
            out[(size_t)((b << 8) + i) * FINAL + 64 + (wv << 4) + ln16] = acc[mt][r];
        }
}

extern "C" void kernel_launch(void* const* d_in, const int* in_sizes, int n_in,
                              void* d_out, int out_size, void* d_ws, size_t ws_size,
                              hipStream_t stream)
{
    const float* node_fea = (const float*)d_in[0];
    const float* edge_fea = (const float*)d_in[1];
    const int*   eidx     = (const int*)  d_in[2];
    const float* dis      = (const float*)d_in[3];
    const float* Wn = (const float*)d_in[4];
    const float* bn = (const float*)d_in[5];
    const float* We = (const float*)d_in[6];
    const float* be = (const float*)d_in[7];
    const float* W1 = (const float*)d_in[8];
    const float* b1 = (const float*)d_in[9];
    const float* a1 = (const float*)d_in[10];
    const float* W2 = (const float*)d_in[11];
    const float* b2 = (const float*)d_in[12];
    const float* a2 = (const float*)d_in[13];
    const float* W3 = (const float*)d_in[14];
    const float* b3 = (const float*)d_in[15];
    const float* a3 = (const float*)d_in[16];
    const float* Wf = (const float*)d_in[17];
    const float* bf = (const float*)d_in[18];
    const float* DAw = (const float*)d_in[19];
    const float* DAb = (const float*)d_in[20];
    float* out = (float*)d_out;

    // workspace layout (bytes, 256-aligned blocks)
    char* base = (char*)d_ws;
    size_t off = 0;
    auto alloc = [&](size_t bytes) { char* p = base + off; off = (off + bytes + 255) & ~(size_t)255; return p; };
    __hip_bfloat16* nfA = (__hip_bfloat16*)alloc((size_t)Bb * Nn * NF * 2);
    __hip_bfloat16* nfB = (__hip_bfloat16*)alloc((size_t)Bb * Nn * NF * 2);
    __hip_bfloat16* W1b = (__hip_bfloat16*)alloc((size_t)SZ_WB * 2);
    __hip_bfloat16* W2b = (__hip_bfloat16*)alloc((size_t)SZ_WB * 2);
    __hip_bfloat16* W3b = (__hip_bfloat16*)alloc((size_t)SZ_WB * 2);
    __hip_bfloat16* W1s = (__hip_bfloat16*)alloc((size_t)SZ_WS * 2);
    __hip_bfloat16* W2s = (__hip_bfloat16*)alloc((size_t)SZ_WS * 2);
    __hip_bfloat16* W3s = (__hip_bfloat16*)alloc((size_t)SZ_WS * 2);
    float* WeT = (float*)alloc((size_t)OEF * EF * 4);
    __hip_bfloat16* DAf = (__hip_bfloat16*)alloc((size_t)Nn * Nn * 2);
    __hip_bfloat16* Wnb = (__hip_bfloat16*)alloc((size_t)SZ_WNB * 2);
    __hip_bfloat16* Web = (__hip_bfloat16*)alloc((size_t)SZ_WEB * 2);
    __hip_bfloat16* Wfb = (__hip_bfloat16*)alloc((size_t)SZ_WFB * 2);
    __hip_bfloat16* XT  = (__hip_bfloat16*)alloc((size_t)Bb * 64 * Nn * 2);
    __hip_bfloat16* efb = (__hip_bfloat16*)alloc((size_t)Bb * Nn * Mm * EF * 2);    // 33.5 MB
    const bool precomp = (ws_size >= off);

    hipLaunchKernelGGL(k_prep, dim3((PREP_TOTAL + 255) / 256), dim3(256), 0, stream,
                       We, W1, W2, W3, Wn, Wf, dis, DAw, DAb,
                       WeT, W1b, W2b, W3b, W1s, W2s, W3s, Wnb, Web, Wfb, DAf);

    hipLaunchKernelGGL(k_embed_all, dim3(precomp ? (256 + Bb * Nn * Mm / 64) : 256), dim3(256), 0, stream,
                       node_fea, Wnb, bn, nfA, edge_fea, Web, be, efb);

    if (precomp) {
        hipLaunchKernelGGL((k_conv_mfma<true>), dim3(Bb * Nn / 4), dim3(256), 0, stream,
                           nfA, edge_fea, efb, eidx, WeT, be, W1b, W1s, b1, a1, nfB);
        hipLaunchKernelGGL((k_conv_mfma<true>), dim3(Bb * Nn / 4), dim3(256), 0, stream,
                           nfB, edge_fea, efb, eidx, WeT, be, W2b, W2s, b2, a2, nfA);
        hipLaunchKernelGGL((k_conv_mfma<true>), dim3(Bb * Nn / 4), dim3(256), 0, stream,
                           nfA, edge_fea, efb, eidx, WeT, be, W3b, W3s, b3, a3, nfB);
    } else {
        hipLaunchKernelGGL((k_conv_mfma<false>), dim3(Bb * Nn / 4), dim3(256), 0, stream,
                           nfA, edge_fea, efb, eidx, WeT, be, W1b, W1s, b1, a1, nfB);
        hipLaunchKernelGGL((k_conv_mfma<false>), dim3(Bb * Nn / 4), dim3(256), 0, stream,
                           nfB, edge_fea, efb, eidx, WeT, be, W2b, W2s, b2, a2, nfA);
        hipLaunchKernelGGL((k_conv_mfma<false>), dim3(Bb * Nn / 4), dim3(256), 0, stream,
                           nfA, edge_fea, efb, eidx, WeT, be, W3b, W3s, b3, a3, nfB);
    }

    hipLaunchKernelGGL(k_final_mfma, dim3(Bb * Nn / 64), dim3(256), 0, stream, nfB, Wfb, bf, out, XT);
    hipLaunchKernelGGL(k_node1_mfma, dim3(Bb * 4), dim3(256), 0, stream, DAf, XT, out);
}